// Round 7
// baseline (113.446 us; speedup 1.0000x reference)
//
#include <hip/hip_runtime.h>

#define NPTS 8192
#define BLOCK 512
#define IB 32                    // i-rows per block (also: points it embeds)
#define NBLK (NPTS / IB)         // 256 blocks
#define NTILES (NPTS / 16)       // 512 j-tiles
#define TPW (NTILES / 8)         // 64 tiles per wave
#define MAGIC 0x13579BDFu

typedef __attribute__((ext_vector_type(8))) short bf16x8;
typedef __attribute__((ext_vector_type(4))) float f32x4;
typedef unsigned short u16;
typedef unsigned int u32;

// arg(base2) = C1*(ni+nj) + K2*dot6 ; closeness^2 = exp2(arg)
#define C1f (-144.26950408889634f)   // -100*log2(e)
#define C2f (-28.853900817779268f)   // out = s*exp2(C2*pen)
#define SQK2f (16.98643596886418f)   // sqrt(200*log2(e))
#define SKIP_TH (-50.0f)             // exp2(-50)*8192 ~ 1e-11 penalty err

static __device__ __forceinline__ u16 f2b(float f) {
    union { float f; u32 u; } v; v.f = f;
    u32 u = v.u;
    return (u16)((u + 0x7FFFu + ((u >> 16) & 1u)) >> 16);   // RN-even
}
static __device__ __forceinline__ float b2f(u16 h) {
    union { u32 u; float f; } v; v.u = ((u32)h) << 16;
    return v.f;
}

struct Split { u16 uh[6], ul[6], ch, cm, cl; float sc; };

static __device__ __forceinline__ Split mksplit(
    const float* __restrict__ src, const float* __restrict__ tgt,
    const float* __restrict__ scores, int p)
{
    float x[6];
    x[0] = src[p * 3 + 0]; x[1] = src[p * 3 + 1]; x[2] = src[p * 3 + 2];
    x[3] = tgt[p * 3 + 0]; x[4] = tgt[p * 3 + 1]; x[5] = tgt[p * 3 + 2];
    float n = 0.0f;
    #pragma unroll
    for (int d = 0; d < 6; d++) n += x[d] * x[d];
    float c = C1f * n;
    Split s;
    #pragma unroll
    for (int d = 0; d < 6; d++) {
        float u = SQK2f * x[d];
        u16   h = f2b(u);
        s.uh[d] = h;
        s.ul[d] = f2b(u - b2f(h));
    }
    s.ch = f2b(c);
    float r1 = c - b2f(s.ch);
    s.cm = f2b(r1);
    s.cl = f2b(r1 - b2f(s.cm));
    s.sc = scores[p];
    return s;
}

#define PK(lo, hi) (((u32)(u16)(lo)) | (((u32)(u16)(hi)) << 16))
static __device__ __forceinline__ void emit_a(const Split& s, uint4* da) {
    const u32 one = 0x3F80u;
    da[0] = make_uint4(PK(s.uh[0],s.uh[1]), PK(s.uh[2],s.uh[3]), PK(s.uh[4],s.uh[5]), PK(s.uh[0],s.uh[1]));
    da[1] = make_uint4(PK(s.uh[2],s.uh[3]), PK(s.uh[4],s.uh[5]), PK(s.ul[0],s.ul[1]), PK(s.ul[2],s.ul[3]));
    da[2] = make_uint4(PK(s.ul[4],s.ul[5]), PK(s.ul[0],s.ul[1]), PK(s.ul[2],s.ul[3]), PK(s.ul[4],s.ul[5]));
    da[3] = make_uint4(PK(s.ch, s.cm),      PK(s.cl, one),       PK(one, one),        0u);
}
static __device__ __forceinline__ void emit_b(const Split& s, uint4* db) {
    const u32 one = 0x3F80u;
    db[0] = make_uint4(PK(s.uh[0],s.uh[1]), PK(s.uh[2],s.uh[3]), PK(s.uh[4],s.uh[5]), PK(s.ul[0],s.ul[1]));
    db[1] = make_uint4(PK(s.ul[2],s.ul[3]), PK(s.ul[4],s.ul[5]), PK(s.uh[0],s.uh[1]), PK(s.uh[2],s.uh[3]));
    db[2] = make_uint4(PK(s.uh[4],s.uh[5]), PK(s.ul[0],s.ul[1]), PK(s.ul[2],s.ul[3]), PK(s.ul[4],s.ul[5]));
    db[3] = make_uint4(PK(one, one),        PK(one, s.ch),       PK(s.cm, s.cl),      0u);
}
#undef PK

// Bg layout (fragment order): tile tt occupies 1024 B; lane l's 16 B at
// tt*1024 + l*16 holds B[k = (l>>4)*8 .. +7][j = tt*16 + (l&15)].
// A-frag: A[m][k], m=lane&15, k=(lane>>4)*8+idx. C/D: col=lane&15, row=(lane>>4)*4+r.
__global__ __launch_bounds__(BLOCK, 4) void softnms_kernel(
    const float* __restrict__ src, const float* __restrict__ tgt,
    const float* __restrict__ scores,
    u16* __restrict__ Bg, u32* __restrict__ flag,
    float* __restrict__ out)
{
    __shared__ uint4 acol[IB * 4];
    __shared__ float sti[IB];
    __shared__ float red[8][IB];

    const int t    = threadIdx.x;
    const int lane = t & 63;
    const int wid  = t >> 6;
    const int half = lane & 15;
    const int quad = lane >> 4;
    const int bid  = blockIdx.x;
    const int i0   = bid * IB;

    // ---- phase 1: embed own 32 points; A-cols -> LDS, B-cols -> global ----
    if (t < IB) {
        Split s = mksplit(src, tgt, scores, i0 + t);
        emit_a(s, &acol[t * 4]);
        sti[t] = s.sc;
        uint4 bcol[4];
        emit_b(s, bcol);
        const int j = i0 + t;
        uint4* Bg4 = (uint4*)Bg;
        #pragma unroll
        for (int q = 0; q < 4; q++)
            Bg4[(j >> 4) * 64 + q * 16 + (j & 15)] = bcol[q];
    }
    __syncthreads();                 // waves drain their stores before signaling

    if (t == 0)
        __hip_atomic_store(&flag[bid], MAGIC, __ATOMIC_RELEASE,
                           __HIP_MEMORY_SCOPE_AGENT);

    // pull A-frags / scores while others arrive
    bf16x8 afrag[2];
    float si[2][4], acc[2][4];
    #pragma unroll
    for (int s = 0; s < 2; s++) {
        afrag[s] = *(const bf16x8*)((const u16*)acol + (s * 16 + half) * 32 + quad * 8);
        #pragma unroll
        for (int r = 0; r < 4; r++) {
            si[s][r]  = sti[s * 16 + quad * 4 + r];
            acc[s][r] = 0.0f;
        }
    }

    // ---- spin barrier: wait until all 256 blocks signaled ----
    int ok;
    do {
        int mine = 1;
        if (t < NBLK) {
            u32 v = __hip_atomic_load(&flag[t], __ATOMIC_ACQUIRE,
                                      __HIP_MEMORY_SCOPE_AGENT);
            mine = (v == MAGIC) ? 1 : 0;
        }
        ok = __syncthreads_and(mine);
    } while (!ok);
    __builtin_amdgcn_fence(__ATOMIC_ACQUIRE, "agent");

    // ---- phase 2: sweep all 512 j-tiles (64 per wave) ----
    const f32x4 zero = {0.0f, 0.0f, 0.0f, 0.0f};
    #pragma unroll 2
    for (int u = 0; u < TPW; u++) {
        const int tile = wid * TPW + u;
        bf16x8 bfrag = *(const bf16x8*)(Bg + (size_t)tile * 512 + lane * 8);
        float  sj    = scores[tile * 16 + half];

        f32x4 d0 = __builtin_amdgcn_mfma_f32_16x16x32_bf16(afrag[0], bfrag, zero, 0, 0, 0);
        f32x4 d1 = __builtin_amdgcn_mfma_f32_16x16x32_bf16(afrag[1], bfrag, zero, 0, 0, 0);

        float m0 = fmaxf(fmaxf(d0[0], d0[1]), fmaxf(d0[2], d0[3]));
        if (__any(m0 > SKIP_TH)) {
            #pragma unroll
            for (int r = 0; r < 4; r++) {
                float e = __builtin_amdgcn_exp2f(d0[r]);
                acc[0][r] += (sj > si[0][r]) ? e : 0.0f;
            }
        }
        float m1 = fmaxf(fmaxf(d1[0], d1[1]), fmaxf(d1[2], d1[3]));
        if (__any(m1 > SKIP_TH)) {
            #pragma unroll
            for (int r = 0; r < 4; r++) {
                float e = __builtin_amdgcn_exp2f(d1[r]);
                acc[1][r] += (sj > si[1][r]) ? e : 0.0f;
            }
        }
    }

    // ---- reduce over 16 j-columns (half bits), then across 8 waves ----
    #pragma unroll
    for (int s = 0; s < 2; s++)
        #pragma unroll
        for (int r = 0; r < 4; r++) {
            float v = acc[s][r];
            v += __shfl_xor(v, 1);
            v += __shfl_xor(v, 2);
            v += __shfl_xor(v, 4);
            v += __shfl_xor(v, 8);
            if (half == 0) red[wid][s * 16 + quad * 4 + r] = v;
        }
    __syncthreads();
    if (t < IB) {
        float p = 0.0f;
        #pragma unroll
        for (int w = 0; w < 8; w++) p += red[w][t];
        out[i0 + t] = sti[t] * __builtin_amdgcn_exp2f(C2f * p);
    }
}

extern "C" void kernel_launch(void* const* d_in, const int* in_sizes, int n_in,
                              void* d_out, int out_size, void* d_ws, size_t ws_size,
                              hipStream_t stream) {
    const float* src    = (const float*)d_in[0];
    const float* tgt    = (const float*)d_in[1];
    const float* scores = (const float*)d_in[2];
    float* out = (float*)d_out;

    u16* Bg   = (u16*)d_ws;                          // 512 KB, frag-ordered
    u32* flag = (u32*)((char*)d_ws + 524288);        // 1 KB arrive flags
    // flags start harness-poisoned (0xAAAAAAAA != MAGIC) -> no reset needed

    softnms_kernel<<<NBLK, BLOCK, 0, stream>>>(src, tgt, scores, Bg, flag, out);
}

// Round 8
// 81.606 us; speedup vs baseline: 1.3902x; 1.3902x over previous
//
#include <hip/hip_runtime.h>

#define NPTS 8192
#define BLOCK 512
#define IB 32                    // i-rows per main block
#define NBLK (NPTS / IB)         // 256 blocks
#define NTILES (NPTS / 16)       // 512 j-tiles
#define TPW (NTILES / 8)         // 64 tiles per wave

typedef __attribute__((ext_vector_type(8))) short bf16x8;
typedef __attribute__((ext_vector_type(4))) float f32x4;
typedef unsigned short u16;
typedef unsigned int u32;

// arg(base2) = C1*(ni+nj) + K2*dot6 ; closeness^2 = exp2(arg)
#define C1f (-144.26950408889634f)   // -100*log2(e)
#define C2f (-28.853900817779268f)   // out = s*exp2(C2*pen)
#define SQK2f (16.98643596886418f)   // sqrt(200*log2(e))
#define SKIP_TH (-50.0f)             // exp2(-50)*8192 ~ 1e-11 penalty err

static __device__ __forceinline__ u16 f2b(float f) {
    union { float f; u32 u; } v; v.f = f;
    u32 u = v.u;
    return (u16)((u + 0x7FFFu + ((u >> 16) & 1u)) >> 16);   // RN-even
}
static __device__ __forceinline__ float b2f(u16 h) {
    union { u32 u; float f; } v; v.u = ((u32)h) << 16;
    return v.f;
}

struct Split { u16 uh[6], ul[6], ch, cm, cl; float sc; };

static __device__ __forceinline__ Split mksplit(
    const float* __restrict__ src, const float* __restrict__ tgt,
    const float* __restrict__ scores, int p)
{
    float x[6];
    x[0] = src[p * 3 + 0]; x[1] = src[p * 3 + 1]; x[2] = src[p * 3 + 2];
    x[3] = tgt[p * 3 + 0]; x[4] = tgt[p * 3 + 1]; x[5] = tgt[p * 3 + 2];
    float n = 0.0f;
    #pragma unroll
    for (int d = 0; d < 6; d++) n += x[d] * x[d];
    float c = C1f * n;
    Split s;
    #pragma unroll
    for (int d = 0; d < 6; d++) {
        float u = SQK2f * x[d];
        u16   h = f2b(u);
        s.uh[d] = h;
        s.ul[d] = f2b(u - b2f(h));
    }
    s.ch = f2b(c);
    float r1 = c - b2f(s.ch);
    s.cm = f2b(r1);
    s.cl = f2b(r1 - b2f(s.cm));
    s.sc = scores[p];
    return s;
}

#define PK(lo, hi) (((u32)(u16)(lo)) | (((u32)(u16)(hi)) << 16))
static __device__ __forceinline__ void emit_a(const Split& s, uint4* da) {
    const u32 one = 0x3F80u;
    da[0] = make_uint4(PK(s.uh[0],s.uh[1]), PK(s.uh[2],s.uh[3]), PK(s.uh[4],s.uh[5]), PK(s.uh[0],s.uh[1]));
    da[1] = make_uint4(PK(s.uh[2],s.uh[3]), PK(s.uh[4],s.uh[5]), PK(s.ul[0],s.ul[1]), PK(s.ul[2],s.ul[3]));
    da[2] = make_uint4(PK(s.ul[4],s.ul[5]), PK(s.ul[0],s.ul[1]), PK(s.ul[2],s.ul[3]), PK(s.ul[4],s.ul[5]));
    da[3] = make_uint4(PK(s.ch, s.cm),      PK(s.cl, one),       PK(one, one),        0u);
}
static __device__ __forceinline__ void emit_b(const Split& s, uint4* db) {
    const u32 one = 0x3F80u;
    db[0] = make_uint4(PK(s.uh[0],s.uh[1]), PK(s.uh[2],s.uh[3]), PK(s.uh[4],s.uh[5]), PK(s.ul[0],s.ul[1]));
    db[1] = make_uint4(PK(s.ul[2],s.ul[3]), PK(s.ul[4],s.ul[5]), PK(s.uh[0],s.uh[1]), PK(s.uh[2],s.uh[3]));
    db[2] = make_uint4(PK(s.uh[4],s.uh[5]), PK(s.ul[0],s.ul[1]), PK(s.ul[2],s.ul[3]), PK(s.ul[4],s.ul[5]));
    db[3] = make_uint4(PK(one, one),        PK(one, s.ch),       PK(s.cm, s.cl),      0u);
}
#undef PK

// Fragment-order tables: tile tt (16 points) occupies 1024 B; lane l's 16 B at
// tt*1024 + l*16 holds column[k = (l>>4)*8 .. +7][pt = tt*16 + (l&15)].
__global__ __launch_bounds__(256) void prep_kernel(
    const float* __restrict__ src, const float* __restrict__ tgt,
    const float* __restrict__ scores,
    u16* __restrict__ Ag, u16* __restrict__ Bg)
{
    const int p = blockIdx.x * 256 + threadIdx.x;
    Split s = mksplit(src, tgt, scores, p);
    uint4 a[4], b[4];
    emit_a(s, a);
    emit_b(s, b);
    uint4* Ag4 = (uint4*)Ag;
    uint4* Bg4 = (uint4*)Bg;
    const int base = (p >> 4) * 64 + (p & 15);
    #pragma unroll
    for (int q = 0; q < 4; q++) {
        Ag4[base + q * 16] = a[q];
        Bg4[base + q * 16] = b[q];
    }
}

// A-frag: A[m][k], m=lane&15, k=(lane>>4)*8+idx. C/D: col=lane&15, row=(lane>>4)*4+r.
__global__ __launch_bounds__(BLOCK, 4) void main_kernel(
    const u16* __restrict__ Ag, const u16* __restrict__ Bg,
    const float* __restrict__ scores, float* __restrict__ out)
{
    __shared__ float red[8][IB];

    const int t    = threadIdx.x;
    const int lane = t & 63;
    const int wid  = t >> 6;
    const int half = lane & 15;
    const int quad = lane >> 4;
    const int i0   = blockIdx.x * IB;

    bf16x8 afrag[2];
    float si[2][4], acc[2][4];
    #pragma unroll
    for (int s = 0; s < 2; s++) {
        afrag[s] = *(const bf16x8*)(Ag + (size_t)(i0 / 16 + s) * 512 + lane * 8);
        #pragma unroll
        for (int r = 0; r < 4; r++) {
            si[s][r]  = scores[i0 + s * 16 + quad * 4 + r];
            acc[s][r] = 0.0f;
        }
    }

    const f32x4 zero = {0.0f, 0.0f, 0.0f, 0.0f};

    #pragma unroll 4
    for (int u = 0; u < TPW; u++) {
        const int tile = wid * TPW + u;
        bf16x8 bfrag = *(const bf16x8*)(Bg + (size_t)tile * 512 + lane * 8);
        float  sj    = scores[tile * 16 + half];

        f32x4 d0 = __builtin_amdgcn_mfma_f32_16x16x32_bf16(afrag[0], bfrag, zero, 0, 0, 0);
        f32x4 d1 = __builtin_amdgcn_mfma_f32_16x16x32_bf16(afrag[1], bfrag, zero, 0, 0, 0);

        float m0 = fmaxf(fmaxf(d0[0], d0[1]), fmaxf(d0[2], d0[3]));
        if (__any(m0 > SKIP_TH)) {
            #pragma unroll
            for (int r = 0; r < 4; r++) {
                float e = __builtin_amdgcn_exp2f(d0[r]);
                acc[0][r] += (sj > si[0][r]) ? e : 0.0f;
            }
        }
        float m1 = fmaxf(fmaxf(d1[0], d1[1]), fmaxf(d1[2], d1[3]));
        if (__any(m1 > SKIP_TH)) {
            #pragma unroll
            for (int r = 0; r < 4; r++) {
                float e = __builtin_amdgcn_exp2f(d1[r]);
                acc[1][r] += (sj > si[1][r]) ? e : 0.0f;
            }
        }
    }

    // reduce over 16 j-columns (half bits), then across 8 waves
    #pragma unroll
    for (int s = 0; s < 2; s++)
        #pragma unroll
        for (int r = 0; r < 4; r++) {
            float v = acc[s][r];
            v += __shfl_xor(v, 1);
            v += __shfl_xor(v, 2);
            v += __shfl_xor(v, 4);
            v += __shfl_xor(v, 8);
            if (half == 0) red[wid][s * 16 + quad * 4 + r] = v;
        }
    __syncthreads();
    if (t < IB) {
        float p = 0.0f;
        #pragma unroll
        for (int w = 0; w < 8; w++) p += red[w][t];
        out[i0 + t] = scores[i0 + t] * __builtin_amdgcn_exp2f(C2f * p);
    }
}

extern "C" void kernel_launch(void* const* d_in, const int* in_sizes, int n_in,
                              void* d_out, int out_size, void* d_ws, size_t ws_size,
                              hipStream_t stream) {
    const float* src    = (const float*)d_in[0];
    const float* tgt    = (const float*)d_in[1];
    const float* scores = (const float*)d_in[2];
    float* out = (float*)d_out;

    u16* Ag = (u16*)d_ws;                        // 512 KB, fragment-ordered
    u16* Bg = (u16*)((char*)d_ws + 524288);      // 512 KB, fragment-ordered

    prep_kernel<<<NPTS / 256, 256, 0, stream>>>(src, tgt, scores, Ag, Bg);
    main_kernel<<<NBLK, BLOCK, 0, stream>>>(Ag, Bg, scores, out);
}

// Round 9
// 76.862 us; speedup vs baseline: 1.4760x; 1.0617x over previous
//
#include <hip/hip_runtime.h>

#define NPTS 8192
#define BLOCK 512
#define IB 32                    // i-rows per main block
#define NBLK (NPTS / IB)         // 256 blocks
#define NTILES (NPTS / 16)       // 512 j-tiles
#define TPW (NTILES / 8)         // 64 tiles per wave

typedef __attribute__((ext_vector_type(8))) short bf16x8;
typedef __attribute__((ext_vector_type(4))) float f32x4;
typedef unsigned short u16;
typedef unsigned int u32;

// arg(base2) = C1*(ni+nj) + K2*dot6 ; closeness^2 = exp2(arg)
#define C1f (-144.26950408889634f)   // -100*log2(e)
#define C2f (-28.853900817779268f)   // out = s*exp2(C2*pen)
#define SQK2f (16.98643596886418f)   // sqrt(200*log2(e))
#define SKIP_TH (-50.0f)             // exp2(-50)*8192 ~ 1e-11 penalty err

static __device__ __forceinline__ u16 f2b(float f) {
    union { float f; u32 u; } v; v.f = f;
    u32 u = v.u;
    return (u16)((u + 0x7FFFu + ((u >> 16) & 1u)) >> 16);   // RN-even
}
static __device__ __forceinline__ float b2f(u16 h) {
    union { u32 u; float f; } v; v.u = ((u32)h) << 16;
    return v.f;
}

struct Split { u16 uh[6], ul[6], ch, cm, cl; float sc; };

static __device__ __forceinline__ Split mksplit(
    const float* __restrict__ src, const float* __restrict__ tgt,
    const float* __restrict__ scores, int p)
{
    float x[6];
    x[0] = src[p * 3 + 0]; x[1] = src[p * 3 + 1]; x[2] = src[p * 3 + 2];
    x[3] = tgt[p * 3 + 0]; x[4] = tgt[p * 3 + 1]; x[5] = tgt[p * 3 + 2];
    float n = 0.0f;
    #pragma unroll
    for (int d = 0; d < 6; d++) n += x[d] * x[d];
    float c = C1f * n;
    Split s;
    #pragma unroll
    for (int d = 0; d < 6; d++) {
        float u = SQK2f * x[d];
        u16   h = f2b(u);
        s.uh[d] = h;
        s.ul[d] = f2b(u - b2f(h));
    }
    s.ch = f2b(c);
    float r1 = c - b2f(s.ch);
    s.cm = f2b(r1);
    s.cl = f2b(r1 - b2f(s.cm));
    s.sc = scores[p];
    return s;
}

#define PK(lo, hi) (((u32)(u16)(lo)) | (((u32)(u16)(hi)) << 16))
static __device__ __forceinline__ void emit_a(const Split& s, uint4* da) {
    const u32 one = 0x3F80u;
    da[0] = make_uint4(PK(s.uh[0],s.uh[1]), PK(s.uh[2],s.uh[3]), PK(s.uh[4],s.uh[5]), PK(s.uh[0],s.uh[1]));
    da[1] = make_uint4(PK(s.uh[2],s.uh[3]), PK(s.uh[4],s.uh[5]), PK(s.ul[0],s.ul[1]), PK(s.ul[2],s.ul[3]));
    da[2] = make_uint4(PK(s.ul[4],s.ul[5]), PK(s.ul[0],s.ul[1]), PK(s.ul[2],s.ul[3]), PK(s.ul[4],s.ul[5]));
    da[3] = make_uint4(PK(s.ch, s.cm),      PK(s.cl, one),       PK(one, one),        0u);
}
static __device__ __forceinline__ void emit_b(const Split& s, uint4* db) {
    const u32 one = 0x3F80u;
    db[0] = make_uint4(PK(s.uh[0],s.uh[1]), PK(s.uh[2],s.uh[3]), PK(s.uh[4],s.uh[5]), PK(s.ul[0],s.ul[1]));
    db[1] = make_uint4(PK(s.ul[2],s.ul[3]), PK(s.ul[4],s.ul[5]), PK(s.uh[0],s.uh[1]), PK(s.uh[2],s.uh[3]));
    db[2] = make_uint4(PK(s.uh[4],s.uh[5]), PK(s.ul[0],s.ul[1]), PK(s.ul[2],s.ul[3]), PK(s.ul[4],s.ul[5]));
    db[3] = make_uint4(PK(one, one),        PK(one, s.ch),       PK(s.cm, s.cl),      0u);
}
#undef PK

// Fragment-order tables: tile tt (16 points) occupies 1024 B; lane l's 16 B at
// tt*1024 + l*16 holds column[k = (l>>4)*8 .. +7][pt = tt*16 + (l&15)].
__global__ __launch_bounds__(256) void prep_kernel(
    const float* __restrict__ src, const float* __restrict__ tgt,
    const float* __restrict__ scores,
    u16* __restrict__ Ag, u16* __restrict__ Bg)
{
    const int p = blockIdx.x * 256 + threadIdx.x;
    Split s = mksplit(src, tgt, scores, p);
    uint4 a[4], b[4];
    emit_a(s, a);
    emit_b(s, b);
    uint4* Ag4 = (uint4*)Ag;
    uint4* Bg4 = (uint4*)Bg;
    const int base = (p >> 4) * 64 + (p & 15);
    #pragma unroll
    for (int q = 0; q < 4; q++) {
        Ag4[base + q * 16] = a[q];
        Bg4[base + q * 16] = b[q];
    }
}

// A-frag: A[m][k], m=lane&15, k=(lane>>4)*8+idx. C/D: col=lane&15, row=(lane>>4)*4+r.
// Tile order is staggered per block so the 256 blocks never hit the same L2
// line simultaneously (anti-hotspot): 8x32 distinct (wave-group, phase) combos.
__global__ __launch_bounds__(BLOCK, 4) void main_kernel(
    const u16* __restrict__ Ag, const u16* __restrict__ Bg,
    const float* __restrict__ scores, float* __restrict__ out)
{
    __shared__ float red[8][IB];

    const int t    = threadIdx.x;
    const int lane = t & 63;
    const int wid  = t >> 6;
    const int half = lane & 15;
    const int quad = lane >> 4;
    const int bx   = blockIdx.x;
    const int i0   = bx * IB;

    const int wgrp  = (wid + bx) & 7;            // staggered wave-group
    const int phase = bx >> 3;                    // staggered start phase

    bf16x8 afrag[2];
    float si[2][4], acc[2][4];
    #pragma unroll
    for (int s = 0; s < 2; s++) {
        afrag[s] = *(const bf16x8*)(Ag + (size_t)(i0 / 16 + s) * 512 + lane * 8);
        #pragma unroll
        for (int r = 0; r < 4; r++) {
            si[s][r]  = scores[i0 + s * 16 + quad * 4 + r];
            acc[s][r] = 0.0f;
        }
    }

    const f32x4 zero = {0.0f, 0.0f, 0.0f, 0.0f};

    #pragma unroll 4
    for (int u = 0; u < TPW; u++) {
        const int tile = wgrp * TPW + ((u + phase) & (TPW - 1));
        bf16x8 bfrag = *(const bf16x8*)(Bg + (size_t)tile * 512 + lane * 8);
        float  sj    = scores[tile * 16 + half];

        f32x4 d0 = __builtin_amdgcn_mfma_f32_16x16x32_bf16(afrag[0], bfrag, zero, 0, 0, 0);
        f32x4 d1 = __builtin_amdgcn_mfma_f32_16x16x32_bf16(afrag[1], bfrag, zero, 0, 0, 0);

        float m0 = fmaxf(fmaxf(d0[0], d0[1]), fmaxf(d0[2], d0[3]));
        if (__any(m0 > SKIP_TH)) {
            #pragma unroll
            for (int r = 0; r < 4; r++) {
                float e = __builtin_amdgcn_exp2f(d0[r]);
                acc[0][r] += (sj > si[0][r]) ? e : 0.0f;
            }
        }
        float m1 = fmaxf(fmaxf(d1[0], d1[1]), fmaxf(d1[2], d1[3]));
        if (__any(m1 > SKIP_TH)) {
            #pragma unroll
            for (int r = 0; r < 4; r++) {
                float e = __builtin_amdgcn_exp2f(d1[r]);
                acc[1][r] += (sj > si[1][r]) ? e : 0.0f;
            }
        }
    }

    // reduce over 16 j-columns (half bits), then across 8 waves
    #pragma unroll
    for (int s = 0; s < 2; s++)
        #pragma unroll
        for (int r = 0; r < 4; r++) {
            float v = acc[s][r];
            v += __shfl_xor(v, 1);
            v += __shfl_xor(v, 2);
            v += __shfl_xor(v, 4);
            v += __shfl_xor(v, 8);
            if (half == 0) red[wid][s * 16 + quad * 4 + r] = v;
        }
    __syncthreads();
    if (t < IB) {
        float p = 0.0f;
        #pragma unroll
        for (int w = 0; w < 8; w++) p += red[w][t];
        out[i0 + t] = scores[i0 + t] * __builtin_amdgcn_exp2f(C2f * p);
    }
}

extern "C" void kernel_launch(void* const* d_in, const int* in_sizes, int n_in,
                              void* d_out, int out_size, void* d_ws, size_t ws_size,
                              hipStream_t stream) {
    const float* src    = (const float*)d_in[0];
    const float* tgt    = (const float*)d_in[1];
    const float* scores = (const float*)d_in[2];
    float* out = (float*)d_out;

    u16* Ag = (u16*)d_ws;                        // 512 KB, fragment-ordered
    u16* Bg = (u16*)((char*)d_ws + 524288);      // 512 KB, fragment-ordered

    prep_kernel<<<NPTS / 256, 256, 0, stream>>>(src, tgt, scores, Ag, Bg);
    main_kernel<<<NBLK, BLOCK, 0, stream>>>(Ag, Bg, scores, out);
}

// Round 10
// 67.579 us; speedup vs baseline: 1.6787x; 1.1374x over previous
//
#include <hip/hip_runtime.h>

#define NPTS 8192
#define BLOCK 1024               // 16 waves, 1 block/CU -> 4 waves/SIMD
#define IB 32                    // i-rows per main block
#define NBLK (NPTS / IB)         // 256 blocks
#define NTILES (NPTS / 16)       // 512 j-tiles
#define NW 16                    // waves per block
#define TPW (NTILES / NW)        // 32 tiles per wave

typedef __attribute__((ext_vector_type(8))) short bf16x8;
typedef __attribute__((ext_vector_type(4))) float f32x4;
typedef unsigned short u16;
typedef unsigned int u32;

// arg(base2) = C1*(ni+nj) + K2*dot6 ; closeness^2 = exp2(arg)
#define C1f (-144.26950408889634f)   // -100*log2(e)
#define C2f (-28.853900817779268f)   // out = s*exp2(C2*pen)
#define SQK2f (16.98643596886418f)   // sqrt(200*log2(e))
#define SKIP_TH (-50.0f)             // exp2(-50)*8192 ~ 1e-11 penalty err

static __device__ __forceinline__ u16 f2b(float f) {
    union { float f; u32 u; } v; v.f = f;
    u32 u = v.u;
    return (u16)((u + 0x7FFFu + ((u >> 16) & 1u)) >> 16);   // RN-even
}
static __device__ __forceinline__ float b2f(u16 h) {
    union { u32 u; float f; } v; v.u = ((u32)h) << 16;
    return v.f;
}

struct Split { u16 uh[6], ul[6], ch, cm, cl; float sc; };

static __device__ __forceinline__ Split mksplit(
    const float* __restrict__ src, const float* __restrict__ tgt,
    const float* __restrict__ scores, int p)
{
    float x[6];
    x[0] = src[p * 3 + 0]; x[1] = src[p * 3 + 1]; x[2] = src[p * 3 + 2];
    x[3] = tgt[p * 3 + 0]; x[4] = tgt[p * 3 + 1]; x[5] = tgt[p * 3 + 2];
    float n = 0.0f;
    #pragma unroll
    for (int d = 0; d < 6; d++) n += x[d] * x[d];
    float c = C1f * n;
    Split s;
    #pragma unroll
    for (int d = 0; d < 6; d++) {
        float u = SQK2f * x[d];
        u16   h = f2b(u);
        s.uh[d] = h;
        s.ul[d] = f2b(u - b2f(h));
    }
    s.ch = f2b(c);
    float r1 = c - b2f(s.ch);
    s.cm = f2b(r1);
    s.cl = f2b(r1 - b2f(s.cm));
    s.sc = scores[p];
    return s;
}

#define PK(lo, hi) (((u32)(u16)(lo)) | (((u32)(u16)(hi)) << 16))
static __device__ __forceinline__ void emit_a(const Split& s, uint4* da) {
    const u32 one = 0x3F80u;
    da[0] = make_uint4(PK(s.uh[0],s.uh[1]), PK(s.uh[2],s.uh[3]), PK(s.uh[4],s.uh[5]), PK(s.uh[0],s.uh[1]));
    da[1] = make_uint4(PK(s.uh[2],s.uh[3]), PK(s.uh[4],s.uh[5]), PK(s.ul[0],s.ul[1]), PK(s.ul[2],s.ul[3]));
    da[2] = make_uint4(PK(s.ul[4],s.ul[5]), PK(s.ul[0],s.ul[1]), PK(s.ul[2],s.ul[3]), PK(s.ul[4],s.ul[5]));
    da[3] = make_uint4(PK(s.ch, s.cm),      PK(s.cl, one),       PK(one, one),        0u);
}
static __device__ __forceinline__ void emit_b(const Split& s, uint4* db) {
    const u32 one = 0x3F80u;
    db[0] = make_uint4(PK(s.uh[0],s.uh[1]), PK(s.uh[2],s.uh[3]), PK(s.uh[4],s.uh[5]), PK(s.ul[0],s.ul[1]));
    db[1] = make_uint4(PK(s.ul[2],s.ul[3]), PK(s.ul[4],s.ul[5]), PK(s.uh[0],s.uh[1]), PK(s.uh[2],s.uh[3]));
    db[2] = make_uint4(PK(s.uh[4],s.uh[5]), PK(s.ul[0],s.ul[1]), PK(s.ul[2],s.ul[3]), PK(s.ul[4],s.ul[5]));
    db[3] = make_uint4(PK(one, one),        PK(one, s.ch),       PK(s.cm, s.cl),      0u);
}
#undef PK

// Fragment-order tables: tile tt (16 points) occupies 1024 B; lane l's 16 B at
// tt*1024 + l*16 holds column[k = (l>>4)*8 .. +7][pt = tt*16 + (l&15)].
__global__ __launch_bounds__(256) void prep_kernel(
    const float* __restrict__ src, const float* __restrict__ tgt,
    const float* __restrict__ scores,
    u16* __restrict__ Ag, u16* __restrict__ Bg)
{
    const int p = blockIdx.x * 256 + threadIdx.x;
    Split s = mksplit(src, tgt, scores, p);
    uint4 a[4], b[4];
    emit_a(s, a);
    emit_b(s, b);
    uint4* Ag4 = (uint4*)Ag;
    uint4* Bg4 = (uint4*)Bg;
    const int base = (p >> 4) * 64 + (p & 15);
    #pragma unroll
    for (int q = 0; q < 4; q++) {
        Ag4[base + q * 16] = a[q];
        Bg4[base + q * 16] = b[q];
    }
}

// A-frag: A[m][k], m=lane&15, k=(lane>>4)*8+idx. C/D: col=lane&15, row=(lane>>4)*4+r.
// 16 waves/block (1 block/CU -> 4 waves/SIMD). Per-block stagger spreads the
// 4096 waves across the 512 tiles (anti L2-hotspot, verified win in R9).
// Register double-buffer on bfrag/sj keeps an L2 load in flight across the
// branchy epilogue.
__global__ __launch_bounds__(BLOCK, 4) void main_kernel(
    const u16* __restrict__ Ag, const u16* __restrict__ Bg,
    const float* __restrict__ scores, float* __restrict__ out)
{
    __shared__ float red[NW][IB];

    const int t    = threadIdx.x;
    const int lane = t & 63;
    const int wid  = t >> 6;
    const int half = lane & 15;
    const int quad = lane >> 4;
    const int bx   = blockIdx.x;
    const int i0   = bx * IB;

    const int wgrp  = (wid + bx) & (NW - 1);     // staggered wave-group
    const int phase = (bx >> 4) & (TPW - 1);     // staggered start phase

    bf16x8 afrag[2];
    float si[2][4], acc[2][4];
    #pragma unroll
    for (int s = 0; s < 2; s++) {
        afrag[s] = *(const bf16x8*)(Ag + (size_t)(bx * 2 + s) * 512 + lane * 8);
        #pragma unroll
        for (int r = 0; r < 4; r++) {
            si[s][r]  = scores[i0 + s * 16 + quad * 4 + r];
            acc[s][r] = 0.0f;
        }
    }

    const f32x4 zero = {0.0f, 0.0f, 0.0f, 0.0f};

    int tile0 = wgrp * TPW + phase;
    bf16x8 bfrag_n = *(const bf16x8*)(Bg + (size_t)tile0 * 512 + lane * 8);
    float  sj_n    = scores[tile0 * 16 + half];

    #pragma unroll 2
    for (int u = 0; u < TPW; u++) {
        bf16x8 bfrag = bfrag_n;
        float  sj    = sj_n;
        // prefetch next (wraps to tile0 on last iter; harmless)
        const int tn = wgrp * TPW + ((u + 1 + phase) & (TPW - 1));
        bfrag_n = *(const bf16x8*)(Bg + (size_t)tn * 512 + lane * 8);
        sj_n    = scores[tn * 16 + half];

        f32x4 d0 = __builtin_amdgcn_mfma_f32_16x16x32_bf16(afrag[0], bfrag, zero, 0, 0, 0);
        f32x4 d1 = __builtin_amdgcn_mfma_f32_16x16x32_bf16(afrag[1], bfrag, zero, 0, 0, 0);

        float m0 = fmaxf(fmaxf(d0[0], d0[1]), fmaxf(d0[2], d0[3]));
        if (__any(m0 > SKIP_TH)) {
            #pragma unroll
            for (int r = 0; r < 4; r++) {
                float e = __builtin_amdgcn_exp2f(d0[r]);
                acc[0][r] += (sj > si[0][r]) ? e : 0.0f;
            }
        }
        float m1 = fmaxf(fmaxf(d1[0], d1[1]), fmaxf(d1[2], d1[3]));
        if (__any(m1 > SKIP_TH)) {
            #pragma unroll
            for (int r = 0; r < 4; r++) {
                float e = __builtin_amdgcn_exp2f(d1[r]);
                acc[1][r] += (sj > si[1][r]) ? e : 0.0f;
            }
        }
    }

    // reduce over 16 j-columns (half bits), then across 16 waves
    #pragma unroll
    for (int s = 0; s < 2; s++)
        #pragma unroll
        for (int r = 0; r < 4; r++) {
            float v = acc[s][r];
            v += __shfl_xor(v, 1);
            v += __shfl_xor(v, 2);
            v += __shfl_xor(v, 4);
            v += __shfl_xor(v, 8);
            if (half == 0) red[wid][s * 16 + quad * 4 + r] = v;
        }
    __syncthreads();
    if (t < IB) {
        float p = 0.0f;
        #pragma unroll
        for (int w = 0; w < NW; w++) p += red[w][t];
        out[i0 + t] = scores[i0 + t] * __builtin_amdgcn_exp2f(C2f * p);
    }
}

extern "C" void kernel_launch(void* const* d_in, const int* in_sizes, int n_in,
                              void* d_out, int out_size, void* d_ws, size_t ws_size,
                              hipStream_t stream) {
    const float* src    = (const float*)d_in[0];
    const float* tgt    = (const float*)d_in[1];
    const float* scores = (const float*)d_in[2];
    float* out = (float*)d_out;

    u16* Ag = (u16*)d_ws;                        // 512 KB, fragment-ordered
    u16* Bg = (u16*)((char*)d_ws + 524288);      // 512 KB, fragment-ordered

    prep_kernel<<<NPTS / 256, 256, 0, stream>>>(src, tgt, scores, Ag, Bg);
    main_kernel<<<NBLK, BLOCK, 0, stream>>>(Ag, Bg, scores, out);
}